// Round 12
// baseline (47.045 us; speedup 1.0000x reference)
//
#include <hip/hip_runtime.h>
#include <hip/hip_bf16.h>

// y = upsample_nearest_2x2x2(conv1x1(x,W,b)); conv on small grid via bf16 MFMA, replicate 8x.
// x: [2][320][16][32][32] f32, W: [160][320] f32, b: [160] f32 -> out: [2][160][32][64][64] f32
//
// v12 = v9 (38.7us) + pipelined prefetch that RIDES ACROSS BARRIERS:
//  - X prefetch depth 2 (HBM ~900cy), W depth 1 (L2 ~200cy).
//  - per-iter issue order: W(c+1) THEN X(c+2) -> stage's counted wait is vmcnt(2),
//    leaving the youngest X generation in flight (vmcnt is an ordered counter).
//  - barrier = sched_barrier(0); s_waitcnt lgkmcnt(0) [no memory clobber];
//    raw s_barrier; sched_barrier(0)  (m201-verified pattern; no vmcnt drain).
//  Race analysis identical to v9: each wave drains its own ds ops (lgkmcnt 0)
//  before the barrier; buf[bs] reuse at c+2 is guarded by barrier c+1.

#define CI     320
#define CO     160
#define S_IN   16384      // 16*32*32
#define KC     32         // K chunk = one MFMA K-step
#define NT     64         // spatial tile per block
#define NCHUNK (CI / KC)  // 10
#define MT     (CO / 16)  // 10 M-tiles

typedef __attribute__((ext_vector_type(8))) short short8;
typedef __attribute__((ext_vector_type(4))) float f32x4;

static __device__ __forceinline__ unsigned short f2bf(float f) {
    __hip_bfloat16 h = __float2bfloat16(f);   // RNE
    unsigned short u;
    __builtin_memcpy(&u, &h, 2);
    return u;
}
static __device__ __forceinline__ unsigned int pack2(float lo, float hi) {
    return (unsigned int)f2bf(lo) | ((unsigned int)f2bf(hi) << 16);
}

__global__ __launch_bounds__(256) void fused_upconv_v12(
    const float* __restrict__ x,
    const float* __restrict__ Wm,
    const float* __restrict__ bias,
    float* __restrict__ out)
{
    // proven 80B-row layout, x2 buffers (35.8 KB total)
    __shared__ unsigned int XsU[2][NT][20];   // [buf][s][k/2]
    __shared__ unsigned int WsU[2][CO][20];   // [buf][o][k/2]

    const int t      = threadIdx.x;
    const int tile   = blockIdx.x;          // 0..255
    const int b      = blockIdx.y;          // 0..1
    const int s_base = tile * NT;
    const float* xb  = x + (size_t)b * CI * S_IN;

    // ---- staging maps (identical to v9) ----
    const int kp = t >> 4;              // k-pair 0..15
    const int s4 = (t & 15) * 4;        // s-quad base
    const int ow = t >> 3;              // W o-base 0..31
    const int kq = t & 7;               // W k-quad 0..7

    float4 xr0[2], xr1[2];              // X generations (parity-indexed, static)
    float4 wr[5];                       // W single generation

    // ---- prologue: issue order X0, W0, X1  (queue: oldest->youngest) ----
    xr0[0] = *(const float4*)&xb[(size_t)(0 + 2 * kp)     * S_IN + s_base + s4];
    xr1[0] = *(const float4*)&xb[(size_t)(0 + 2 * kp + 1) * S_IN + s_base + s4];
    #pragma unroll
    for (int it = 0; it < 5; ++it)
        wr[it] = *(const float4*)&Wm[(size_t)(ow + it * 32) * CI + kq * 4];
    xr0[1] = *(const float4*)&xb[(size_t)(KC + 2 * kp)     * S_IN + s_base + s4];
    xr1[1] = *(const float4*)&xb[(size_t)(KC + 2 * kp + 1) * S_IN + s_base + s4];

    // ---- fragment indices (identical to v9) ----
    const int lane = t & 63;
    const int wid  = t >> 6;        // wave -> 16-s subtile
    const int frow = lane & 15;
    const int fk   = lane >> 4;

    f32x4 acc[MT];
    #pragma unroll
    for (int mt = 0; mt < MT; ++mt) acc[mt] = (f32x4){0.f, 0.f, 0.f, 0.f};

    #pragma unroll
    for (int c = 0; c < NCHUNK; ++c) {
        const int bs = c & 1;       // compile-time after unroll

        // stage gen-c -> LDS buf[bs]: consumes X gen c (vmcnt leaves younger) + W gen c
        {
            const float xa[4] = {xr0[bs].x, xr0[bs].y, xr0[bs].z, xr0[bs].w};
            const float xc[4] = {xr1[bs].x, xr1[bs].y, xr1[bs].z, xr1[bs].w};
            #pragma unroll
            for (int j = 0; j < 4; ++j)
                XsU[bs][s4 + j][kp] = pack2(xa[j], xc[j]);   // k=2kp low, 2kp+1 high
            #pragma unroll
            for (int it = 0; it < 5; ++it) {
                uint2 p = make_uint2(pack2(wr[it].x, wr[it].y), pack2(wr[it].z, wr[it].w));
                *(uint2*)&WsU[bs][ow + it * 32][kq * 2] = p;
            }
        }

        // issue W gen-(c+1) FIRST, then X gen-(c+2): keeps the youngest X behind W
        // in the vmcnt queue so next stage's wait is vmcnt(2), not vmcnt(0).
        if (c + 1 < NCHUNK) {
            const int kc = (c + 1) * KC;
            #pragma unroll
            for (int it = 0; it < 5; ++it)
                wr[it] = *(const float4*)&Wm[(size_t)(ow + it * 32) * CI + kc + kq * 4];
        }
        if (c + 2 < NCHUNK) {
            const int kc = (c + 2) * KC;
            xr0[bs] = *(const float4*)&xb[(size_t)(kc + 2 * kp)     * S_IN + s_base + s4];
            xr1[bs] = *(const float4*)&xb[(size_t)(kc + 2 * kp + 1) * S_IN + s_base + s4];
        }

        // barrier WITHOUT vmcnt drain: own LDS ops complete; prefetch rides across.
        __builtin_amdgcn_sched_barrier(0);
        asm volatile("s_waitcnt lgkmcnt(0)");
        __builtin_amdgcn_s_barrier();
        __builtin_amdgcn_sched_barrier(0);

        // compute chunk c from buf[bs]
        const short8 bfrag =
            *(const short8*)((const char*)(&XsU[bs][wid * 16 + frow][0]) + fk * 16);
        #pragma unroll
        for (int mt = 0; mt < MT; ++mt) {
            const short8 afrag =
                *(const short8*)((const char*)(&WsU[bs][mt * 16 + frow][0]) + fk * 16);
            acc[mt] = __builtin_amdgcn_mfma_f32_16x16x32_bf16(afrag, bfrag, acc[mt], 0, 0, 0);
        }
    }

    // ---- epilogue (identical to v9): bias + replicate 8x; shfl-pair float4 stores ----
    const int s   = s_base + wid * 16 + frow;   // D col = s
    const int dd  = s >> 10;
    const int hh  = (s >> 5) & 31;
    const int wc  = s & 31;
    const int odd = lane & 1;
    const int wc0 = wc & ~1;

    #pragma unroll
    for (int mt = 0; mt < MT; ++mt) {
        #pragma unroll
        for (int j = 0; j < 4; ++j) {
            const int o = mt * 16 + fk * 4 + j; // D row = o
            float v  = acc[mt][j] + bias[o];
            float vp = __shfl_xor(v, 1);
            float lo = odd ? vp : v;
            float hi = odd ? v : vp;
            float4 q = make_float4(lo, lo, hi, hi);
            const size_t base = (((size_t)(b * CO + o) * 32) + (size_t)(2 * dd + odd)) * 4096
                              + (size_t)(2 * hh) * 64 + (size_t)(2 * wc0);
            *(float4*)&out[base]      = q;
            *(float4*)&out[base + 64] = q;
        }
    }
}

extern "C" void kernel_launch(void* const* d_in, const int* in_sizes, int n_in,
                              void* d_out, int out_size, void* d_ws, size_t ws_size,
                              hipStream_t stream) {
    const float* x    = (const float*)d_in[0];
    const float* Wm   = (const float*)d_in[1];
    const float* bias = (const float*)d_in[2];
    float* out        = (float*)d_out;

    dim3 grid(S_IN / NT, 2);   // (256, 2) = 512 blocks
    dim3 block(256);
    fused_upconv_v12<<<grid, block, 0, stream>>>(x, Wm, bias, out);
}